// Round 12
// baseline (2595.706 us; speedup 1.0000x reference)
//
#include <hip/hip_runtime.h>
#include <hip/hip_bf16.h>
#include <hip/hip_fp16.h>
#include <math.h>

#define NROW 16384
#define DIN 32

typedef _Float16 f16x8 __attribute__((ext_vector_type(8)));
typedef float f32x4 __attribute__((ext_vector_type(4)));
typedef unsigned int u32x2 __attribute__((ext_vector_type(2)));

constexpr int MM_KSEG = 16;
constexpr int MM_SEGK = NROW / MM_KSEG;   // 1024 k per segment
constexpr int MM_KSTEPS = MM_SEGK / 32;   // 32 mfma K-steps per segment
constexpr int KMAX = 3;                   // truncation (validated r10/r11)

constexpr float LSCALE     = 128.f;       // lift L out of e4m3 subnormal range
constexpr float LSCALE_INV = 1.f / 128.f;

// fp8 fragment-packed Lh: 512 B contiguous per 16x32 fragment.
// order: [g64=i/64][kseg][s][t][lane][8B]. B-layout: Bp[k>>3][j][k&7].
constexpr size_t FRAG8 = 512;
constexpr size_t STEP8 = 4 * FRAG8;
constexpr size_t WSEG8 = (size_t)MM_KSTEPS * STEP8;  // 64 KB per (g64,kseg)

// ---------------------------------------------------------------------------
// agent-scope acquire float4 load (bypasses non-coherent per-XCD caches)
// ---------------------------------------------------------------------------
__device__ inline float4 yp_acq_load(const float* p)
{
    unsigned long long a = __hip_atomic_load((const unsigned long long*)p,
                                             __ATOMIC_ACQUIRE, __HIP_MEMORY_SCOPE_AGENT);
    unsigned long long b = __hip_atomic_load(((const unsigned long long*)p) + 1,
                                             __ATOMIC_ACQUIRE, __HIP_MEMORY_SCOPE_AGENT);
    float4 r;
    r.x = __uint_as_float((unsigned)(a & 0xffffffffull));
    r.y = __uint_as_float((unsigned)(a >> 32));
    r.z = __uint_as_float((unsigned)(b & 0xffffffffull));
    r.w = __uint_as_float((unsigned)(b >> 32));
    return r;
}

// ---------------------------------------------------------------------------
// Fused reduction: sum 16 Yp partials for row-group bx (256 rows), apply
// recurrence + LP/HPc accumulation, emit Tnext + fp8 hi/lo pack (unless last).
// Fixed s=0..15 order -> bit-identical to the old separate epilogue.
// ---------------------------------------------------------------------------
__device__ inline void reduce_rows(const float* __restrict__ Yp,
                                   const float* __restrict__ X,
                                   const float* __restrict__ Tprev,
                                   float* __restrict__ Tnext,
                                   unsigned char* __restrict__ Thi,
                                   unsigned char* __restrict__ Tlo,
                                   float* __restrict__ LP, float* __restrict__ HPc,
                                   float cl, float ch, float cl0, float ch0,
                                   int first, int last, int bx)
{
    const size_t stride = (size_t)NROW * DIN / 4;   // 131072 float4 units/seg
    for (int u = threadIdx.x; u < 2048; u += 256) {
        const int g = bx * 2048 + u;

        float4 y = make_float4(0.f, 0.f, 0.f, 0.f);
#pragma unroll
        for (int s = 0; s < MM_KSEG; ++s) {
            float4 p = yp_acq_load(Yp + ((size_t)s * stride + g) * 4);
            y.x += p.x; y.y += p.y; y.z += p.z; y.w += p.w;
        }

        float4 t;
        if (first) {
            float4 x = ((const float4*)X)[g];
            t = y;
            ((float4*)LP)[g]  = make_float4(cl0 * x.x + cl * y.x, cl0 * x.y + cl * y.y,
                                            cl0 * x.z + cl * y.z, cl0 * x.w + cl * y.w);
            ((float4*)HPc)[g] = make_float4(ch0 * x.x + ch * y.x, ch0 * x.y + ch * y.y,
                                            ch0 * x.z + ch * y.z, ch0 * x.w + ch * y.w);
        } else {
            float4 tp = ((const float4*)Tprev)[g];
            t = make_float4(2.f * y.x - tp.x, 2.f * y.y - tp.y,
                            2.f * y.z - tp.z, 2.f * y.w - tp.w);
            float4 l = ((float4*)LP)[g];
            l.x += cl * t.x; l.y += cl * t.y; l.z += cl * t.z; l.w += cl * t.w;
            ((float4*)LP)[g] = l;
            float4 h = ((float4*)HPc)[g];
            h.x += ch * t.x; h.y += ch * t.y; h.z += ch * t.z; h.w += ch * t.w;
            ((float4*)HPc)[g] = h;
        }

        if (!last) {
            ((float4*)Tnext)[g] = t;
            // pack t -> fp8 hi/lo B-layout for the next MFMA pass
            const int k = g >> 3, q = g & 7, j0 = q * 4;
            unsigned char* th = Thi + (size_t)(k >> 3) * 256 + (k & 7);
            unsigned char* tl = Tlo + (size_t)(k >> 3) * 256 + (k & 7);
            unsigned int h01 = __builtin_amdgcn_cvt_pk_fp8_f32(t.x, t.y, 0, false);
            unsigned int h23 = __builtin_amdgcn_cvt_pk_fp8_f32(t.z, t.w, 0, false);
            float rx = __builtin_amdgcn_cvt_f32_fp8(h01, 0);
            float ry = __builtin_amdgcn_cvt_f32_fp8(h01, 1);
            float rz = __builtin_amdgcn_cvt_f32_fp8(h23, 0);
            float rw = __builtin_amdgcn_cvt_f32_fp8(h23, 1);
            unsigned int l01 = __builtin_amdgcn_cvt_pk_fp8_f32(t.x - rx, t.y - ry, 0, false);
            unsigned int l23 = __builtin_amdgcn_cvt_pk_fp8_f32(t.z - rz, t.w - rw, 0, false);
            th[(j0 + 0) * 8] = (unsigned char)(h01 & 0xff);
            th[(j0 + 1) * 8] = (unsigned char)((h01 >> 8) & 0xff);
            th[(j0 + 2) * 8] = (unsigned char)(h23 & 0xff);
            th[(j0 + 3) * 8] = (unsigned char)((h23 >> 8) & 0xff);
            tl[(j0 + 0) * 8] = (unsigned char)(l01 & 0xff);
            tl[(j0 + 1) * 8] = (unsigned char)((l01 >> 8) & 0xff);
            tl[(j0 + 2) * 8] = (unsigned char)(l23 & 0xff);
            tl[(j0 + 3) * 8] = (unsigned char)((l23 >> 8) & 0xff);
        }
    }
}

// ---------------------------------------------------------------------------
// last-block ticket: returns true for the one block that should reduce bx.
// ---------------------------------------------------------------------------
__device__ inline bool take_last_ticket(unsigned int* cnt)
{
    __threadfence();
    __shared__ unsigned int s_ticket;
    if (threadIdx.x == 0)
        s_ticket = __hip_atomic_fetch_add(&cnt[blockIdx.x], 1u,
                                          __ATOMIC_ACQ_REL, __HIP_MEMORY_SCOPE_AGENT);
    __syncthreads();
    if (s_ticket != (unsigned)(MM_KSEG - 1)) return false;
    __threadfence();
    return true;
}

// pack X (fp32 [k][32]) -> Xp fp16 packed B-layout. One float4 per thread.
__global__ __launch_bounds__(256)
void pack_x(const float* __restrict__ X, _Float16* __restrict__ Xp)
{
    const int g = blockIdx.x * 256 + threadIdx.x;
    const int k = g >> 3, q = g & 7, j0 = q * 4;
    float4 v = ((const float4*)X)[g];
    _Float16* tp = Xp + (size_t)(k >> 3) * 256 + (k & 7);
    tp[(j0 + 0) * 8] = (_Float16)v.x;
    tp[(j0 + 1) * 8] = (_Float16)v.y;
    tp[(j0 + 2) * 8] = (_Float16)v.z;
    tp[(j0 + 3) * 8] = (_Float16)v.w;
}

// ---------------------------------------------------------------------------
// Pass 1 (fused): Yp[seg] = L(fp32) @ Xp via f16 MFMA; emit fp8 Lh; the last
// kseg-block per row-group reduces (first=1: T1=Y, LP/HPc init, pack T1).
// ---------------------------------------------------------------------------
__global__ __launch_bounds__(256)
void mm_pass1(const float* __restrict__ L, const _Float16* __restrict__ Xp,
              const float* __restrict__ X,
              float* __restrict__ Yp, unsigned char* __restrict__ Lh,
              float* __restrict__ T1out,
              unsigned char* __restrict__ Thi, unsigned char* __restrict__ Tlo,
              float* __restrict__ LP, float* __restrict__ HPc,
              unsigned int* __restrict__ cnt,
              float cl, float ch, float cl0, float ch0)
{
    const int wave = threadIdx.x >> 6, lane = threadIdx.x & 63;
    const int gr = lane >> 4, m = lane & 15;
    const int i0 = blockIdx.x * 256 + wave * 64;
    const int kseg = blockIdx.y;
    const int kb0 = kseg * MM_SEGK;
    const int g64 = blockIdx.x * 4 + wave;

    f32x4 acc[4][2];
#pragma unroll
    for (int t = 0; t < 4; ++t) { acc[t][0] = (f32x4)0.f; acc[t][1] = (f32x4)0.f; }

    const float* ap = L + (size_t)(i0 + m) * NROW + kb0 + gr * 8;
    unsigned char* sp = Lh + ((size_t)g64 * MM_KSEG + kseg) * WSEG8 + (size_t)lane * 8;
    const _Float16* bp = Xp + ((size_t)(kb0 >> 3) + gr) * 256 + m * 8;

    for (int s = 0; s < MM_KSTEPS; ++s) {
        f16x8 b0 = *(const f16x8*)(bp);
        f16x8 b1 = *(const f16x8*)(bp + 128);
        bp += 1024;
#pragma unroll
        for (int t = 0; t < 4; ++t) {
            const float* a32 = ap + (size_t)t * 16 * NROW;
            f32x4 u = __builtin_nontemporal_load((const f32x4*)a32);
            f32x4 v = __builtin_nontemporal_load((const f32x4*)(a32 + 4));
            f16x8 a;
            a[0] = (_Float16)u[0]; a[1] = (_Float16)u[1];
            a[2] = (_Float16)u[2]; a[3] = (_Float16)u[3];
            a[4] = (_Float16)v[0]; a[5] = (_Float16)v[1];
            a[6] = (_Float16)v[2]; a[7] = (_Float16)v[3];
            unsigned int p0 = __builtin_amdgcn_cvt_pk_fp8_f32(u[0] * LSCALE, u[1] * LSCALE, 0, false);
            p0 = __builtin_amdgcn_cvt_pk_fp8_f32(u[2] * LSCALE, u[3] * LSCALE, p0, true);
            unsigned int p1 = __builtin_amdgcn_cvt_pk_fp8_f32(v[0] * LSCALE, v[1] * LSCALE, 0, false);
            p1 = __builtin_amdgcn_cvt_pk_fp8_f32(v[2] * LSCALE, v[3] * LSCALE, p1, true);
            u32x2 pk; pk[0] = p0; pk[1] = p1;
            __builtin_nontemporal_store(pk, (u32x2*)(sp + t * FRAG8));
            acc[t][0] = __builtin_amdgcn_mfma_f32_16x16x32_f16(a, b0, acc[t][0], 0, 0, 0);
            acc[t][1] = __builtin_amdgcn_mfma_f32_16x16x32_f16(a, b1, acc[t][1], 0, 0, 0);
        }
        ap += 32; sp += STEP8;
    }

#pragma unroll
    for (int t = 0; t < 4; ++t)
#pragma unroll
        for (int jt = 0; jt < 2; ++jt) {
            const int row = i0 + t * 16 + gr * 4;
            float* yb = Yp + ((size_t)kseg * NROW + row) * DIN + jt * 16 + m;
#pragma unroll
            for (int r = 0; r < 4; ++r) yb[(size_t)r * DIN] = acc[t][jt][r];
        }

    if (take_last_ticket(cnt))
        reduce_rows(Yp, X, X, T1out, Thi, Tlo, LP, HPc,
                    cl, ch, cl0, ch0, 1, 0, blockIdx.x);
}

// ---------------------------------------------------------------------------
// Passes 2..KMAX (fused): Yp[seg] = (Lh fp8 @ (T_hi+T_lo) fp8)/128; last
// kseg-block per row-group reduces (recurrence + LP/HPc; pack unless last).
// ---------------------------------------------------------------------------
__global__ __launch_bounds__(256)
void mm_passH(const unsigned char* __restrict__ Lh,
              const unsigned char* __restrict__ Bhi,
              const unsigned char* __restrict__ Blo,
              const float* __restrict__ Tprev, float* __restrict__ Tnext,
              unsigned char* __restrict__ Thi, unsigned char* __restrict__ Tlo,
              float* __restrict__ LP, float* __restrict__ HPc,
              float* __restrict__ Yp, unsigned int* __restrict__ cnt,
              float cl, float ch, int last)
{
    const int wave = threadIdx.x >> 6, lane = threadIdx.x & 63;
    const int gr = lane >> 4, m = lane & 15;
    const int i0 = blockIdx.x * 256 + wave * 64;
    const int kseg = blockIdx.y;
    const int kb0 = kseg * MM_SEGK;
    const int g64 = blockIdx.x * 4 + wave;

    f32x4 acc[4][2];
#pragma unroll
    for (int t = 0; t < 4; ++t) { acc[t][0] = (f32x4)0.f; acc[t][1] = (f32x4)0.f; }

    const unsigned char* ap = Lh + ((size_t)g64 * MM_KSEG + kseg) * WSEG8 + (size_t)lane * 8;
    const unsigned char* bph = Bhi + ((size_t)(kb0 >> 3) + gr) * 256 + m * 8;
    const unsigned char* bpl = Blo + ((size_t)(kb0 >> 3) + gr) * 256 + m * 8;

#pragma unroll 2
    for (int s = 0; s < MM_KSTEPS; ++s) {
        long bh0 = *(const long*)(bph);
        long bh1 = *(const long*)(bph + 128);
        long bl0 = *(const long*)(bpl);
        long bl1 = *(const long*)(bpl + 128);
        bph += 1024; bpl += 1024;
#pragma unroll
        for (int t = 0; t < 4; ++t) {
            long at = __builtin_nontemporal_load((const long*)(ap + t * FRAG8));
            acc[t][0] = __builtin_amdgcn_mfma_f32_16x16x32_fp8_fp8(at, bh0, acc[t][0], 0, 0, 0);
            acc[t][0] = __builtin_amdgcn_mfma_f32_16x16x32_fp8_fp8(at, bl0, acc[t][0], 0, 0, 0);
            acc[t][1] = __builtin_amdgcn_mfma_f32_16x16x32_fp8_fp8(at, bh1, acc[t][1], 0, 0, 0);
            acc[t][1] = __builtin_amdgcn_mfma_f32_16x16x32_fp8_fp8(at, bl1, acc[t][1], 0, 0, 0);
        }
        ap += STEP8;
    }

#pragma unroll
    for (int t = 0; t < 4; ++t)
#pragma unroll
        for (int jt = 0; jt < 2; ++jt) {
            const int row = i0 + t * 16 + gr * 4;
            float* yb = Yp + ((size_t)kseg * NROW + row) * DIN + jt * 16 + m;
#pragma unroll
            for (int r = 0; r < 4; ++r) yb[(size_t)r * DIN] = acc[t][jt][r] * LSCALE_INV;
        }

    if (take_last_ticket(cnt))
        reduce_rows(Yp, nullptr, Tprev, Tnext, Thi, Tlo, LP, HPc,
                    cl, ch, 0.f, 0.f, 0, last, blockIdx.x);
}

// ---------------------------------------------------------------------------
// Final fuse: HP = X - HPc; H_lp = relu(LP@Wlp+b); H_hp = relu(HP@Whp+b);
// Z = [H_lp, H_hp, X] @ Wf + bf  -> fp32 out. One thread per row.
// ---------------------------------------------------------------------------
__global__ __launch_bounds__(256)
void cheb_final(const float* __restrict__ X, const float* __restrict__ LP,
                const float* __restrict__ HPc,
                const float* __restrict__ Wlp, const float* __restrict__ blp,
                const float* __restrict__ Whp, const float* __restrict__ bhp,
                const float* __restrict__ Wf, const float* __restrict__ bf,
                float* __restrict__ Z)
{
    const int row = blockIdx.x * 256 + threadIdx.x;
    const size_t base = (size_t)row * DIN;

    float x[DIN], lp[DIN], hp[DIN];
#pragma unroll
    for (int q = 0; q < DIN / 4; ++q) {
        float4 xv = ((const float4*)(X + base))[q];
        float4 lv = ((const float4*)(LP + base))[q];
        float4 hv = ((const float4*)(HPc + base))[q];
        x[4 * q + 0] = xv.x; x[4 * q + 1] = xv.y; x[4 * q + 2] = xv.z; x[4 * q + 3] = xv.w;
        lp[4 * q + 0] = lv.x; lp[4 * q + 1] = lv.y; lp[4 * q + 2] = lv.z; lp[4 * q + 3] = lv.w;
        hp[4 * q + 0] = xv.x - hv.x; hp[4 * q + 1] = xv.y - hv.y;
        hp[4 * q + 2] = xv.z - hv.z; hp[4 * q + 3] = xv.w - hv.w;
    }

    float h1[DIN];
#pragma unroll
    for (int j = 0; j < DIN; ++j) h1[j] = blp[j];
    for (int d = 0; d < DIN; ++d) {
        float v = lp[d];
#pragma unroll
        for (int j = 0; j < DIN; ++j) h1[j] += v * Wlp[d * DIN + j];
    }
#pragma unroll
    for (int j = 0; j < DIN; ++j) h1[j] = fmaxf(h1[j], 0.f);

    float h2[DIN];
#pragma unroll
    for (int j = 0; j < DIN; ++j) h2[j] = bhp[j];
    for (int d = 0; d < DIN; ++d) {
        float v = hp[d];
#pragma unroll
        for (int j = 0; j < DIN; ++j) h2[j] += v * Whp[d * DIN + j];
    }
#pragma unroll
    for (int j = 0; j < DIN; ++j) h2[j] = fmaxf(h2[j], 0.f);

    float z[DIN];
#pragma unroll
    for (int j = 0; j < DIN; ++j) z[j] = bf[j];
    for (int o = 0; o < DIN; ++o) {
        float v = h1[o];
#pragma unroll
        for (int j = 0; j < DIN; ++j) z[j] += v * Wf[o * DIN + j];
    }
    for (int o = 0; o < DIN; ++o) {
        float v = h2[o];
#pragma unroll
        for (int j = 0; j < DIN; ++j) z[j] += v * Wf[(DIN + o) * DIN + j];
    }
    for (int d = 0; d < DIN; ++d) {
        float v = x[d];
#pragma unroll
        for (int j = 0; j < DIN; ++j) z[j] += v * Wf[(2 * DIN + d) * DIN + j];
    }

#pragma unroll
    for (int q = 0; q < DIN / 4; ++q)
        ((float4*)(Z + base))[q] =
            make_float4(z[4 * q + 0], z[4 * q + 1], z[4 * q + 2], z[4 * q + 3]);
}

// ---------------------------------------------------------------------------
static double factd(int n) { double f = 1.0; for (int i = 2; i <= n; ++i) f *= i; return f; }

static void cheb_coeffs(double tau, double* a)
{
    for (int k = 0; k <= 8; ++k) {
        double s = 0.0;
        for (int m = 0; m < 40; ++m)
            s += pow(tau * 0.5, 2 * m + k) / (factd(m) * factd(m + k));
        a[k] = (k > 0 ? 2.0 : 1.0) * ((k & 1) ? -1.0 : 1.0) * exp(-tau) * s;
    }
}

extern "C" void kernel_launch(void* const* d_in, const int* in_sizes, int n_in,
                              void* d_out, int out_size, void* d_ws, size_t ws_size,
                              hipStream_t stream)
{
    const float* X   = (const float*)d_in[0];
    const float* L   = (const float*)d_in[1];
    const float* Wlp = (const float*)d_in[2];
    const float* blp = (const float*)d_in[3];
    const float* Whp = (const float*)d_in[4];
    const float* bhp = (const float*)d_in[5];
    const float* Wf  = (const float*)d_in[6];
    const float* bf  = (const float*)d_in[7];
    float* Z = (float*)d_out;

    const size_t TBUF = (size_t)NROW * DIN;          // 524288 elements
    char* base = (char*)d_ws;
    unsigned char* Lh = (unsigned char*)base;        // 256 MiB fp8 fragment-packed
    float* Yp  = (float*)(base + (size_t)NROW * NROW);      // 16 x 2 MiB
    float* A   = Yp + (size_t)MM_KSEG * TBUF;
    float* Bu  = A + TBUF;
    float* LP  = Bu + TBUF;
    float* HPc = LP + TBUF;
    unsigned char* Thi = (unsigned char*)(HPc + TBUF);      // 0.5 MiB
    unsigned char* Tlo = Thi + TBUF;                        // 0.5 MiB
    _Float16* Xp = (_Float16*)(Tlo + TBUF);                 // 1 MiB
    unsigned int* cnt = (unsigned int*)(Xp + TBUF);         // 3 x 64 counters

    double alp[9], ahp[9];
    cheb_coeffs(0.5, alp);   // TAU_LP
    cheb_coeffs(1.5, ahp);   // TAU_HP

    dim3 mmGrid(NROW / 256, MM_KSEG);                // (64, 16)
    const int epiBlocks = NROW * DIN / 4 / 256;      // 512

    hipMemsetAsync(cnt, 0, 3 * 64 * sizeof(unsigned int), stream);
    pack_x<<<epiBlocks, 256, 0, stream>>>(X, Xp);

    // pass 1: T1 = L @ X (f16 MFMA; emits fp8 Lh; fused reduction/pack)
    mm_pass1<<<mmGrid, 256, 0, stream>>>(L, Xp, X, Yp, Lh, A, Thi, Tlo, LP, HPc,
        cnt, (float)alp[1], (float)ahp[1], (float)alp[0], (float)ahp[0]);

    // pass 2: T2 = 2 L T1 - X   (Tprev = X, Tnext = Bu, pack for pass 3)
    mm_passH<<<mmGrid, 256, 0, stream>>>(Lh, Thi, Tlo, X, Bu, Thi, Tlo, LP, HPc,
        Yp, cnt + 64, (float)alp[2], (float)ahp[2], 0);

    // pass 3 (last): T3 = 2 L T2 - T1  (Tprev = A; no Tnext/pack)
    mm_passH<<<mmGrid, 256, 0, stream>>>(Lh, Thi, Tlo, A, nullptr, nullptr, nullptr,
        LP, HPc, Yp, cnt + 128, (float)alp[3], (float)ahp[3], 1);

    cheb_final<<<NROW / 256, 256, 0, stream>>>(X, LP, HPc, Wlp, blp, Whp, bhp,
                                               Wf, bf, Z);
}

// Round 13
// 505.836 us; speedup vs baseline: 5.1315x; 5.1315x over previous
//
#include <hip/hip_runtime.h>
#include <hip/hip_bf16.h>
#include <hip/hip_fp16.h>
#include <math.h>

#define NROW 16384
#define DIN 32

typedef _Float16 f16x8 __attribute__((ext_vector_type(8)));
typedef _Float16 f16x4 __attribute__((ext_vector_type(4)));
typedef float f32x4 __attribute__((ext_vector_type(4)));
typedef unsigned int u32x2 __attribute__((ext_vector_type(2)));

constexpr int MM_KSEG = 16;
constexpr int MM_SEGK = NROW / MM_KSEG;   // 1024 k per segment
constexpr int MM_KSTEPS = MM_SEGK / 32;   // 32 mfma K-steps per segment

constexpr float LSCALE     = 128.f;       // lift L out of e4m3 subnormal range
constexpr float LSCALE_INV = 1.f / 128.f;

// fp8 fragment-packed Lh: 512 B contiguous per 16x32 fragment.
// order: [g64=i/64][kseg][s][t][lane][8B]. B-layout: Bp[k>>3][j][k&7].
constexpr size_t FRAG8 = 512;
constexpr size_t STEP8 = 4 * FRAG8;
constexpr size_t WSEG8 = (size_t)MM_KSTEPS * STEP8;  // 64 KB per (g64,kseg)

// pack X (fp32 [k][32]) -> Xp fp16 packed B-layout. One float4 per thread.
__global__ __launch_bounds__(256)
void pack_x(const float* __restrict__ X, _Float16* __restrict__ Xp)
{
    const int g = blockIdx.x * 256 + threadIdx.x;
    const int k = g >> 3, q = g & 7, j0 = q * 4;
    float4 v = ((const float4*)X)[g];
    _Float16* tp = Xp + (size_t)(k >> 3) * 256 + (k & 7);
    tp[(j0 + 0) * 8] = (_Float16)v.x;
    tp[(j0 + 1) * 8] = (_Float16)v.y;
    tp[(j0 + 2) * 8] = (_Float16)v.z;
    tp[(j0 + 3) * 8] = (_Float16)v.w;
}

// ---------------------------------------------------------------------------
// Pass 1: Yp16[seg] = L(fp32) @ Xp via f16 MFMA (accurate T1); emit
// Lh = e4m3(128*L) fragment-packed. fp16 partials (halved write traffic).
// ---------------------------------------------------------------------------
__global__ __launch_bounds__(256)
void mm_pass1(const float* __restrict__ L, const _Float16* __restrict__ Xp,
              _Float16* __restrict__ Yp16, unsigned char* __restrict__ Lh)
{
    const int wave = threadIdx.x >> 6, lane = threadIdx.x & 63;
    const int gr = lane >> 4, m = lane & 15;
    const int i0 = blockIdx.x * 256 + wave * 64;
    const int kseg = blockIdx.y;
    const int kb0 = kseg * MM_SEGK;
    const int g64 = blockIdx.x * 4 + wave;

    f32x4 acc[4][2];
#pragma unroll
    for (int t = 0; t < 4; ++t) { acc[t][0] = (f32x4)0.f; acc[t][1] = (f32x4)0.f; }

    const float* ap = L + (size_t)(i0 + m) * NROW + kb0 + gr * 8;
    unsigned char* sp = Lh + ((size_t)g64 * MM_KSEG + kseg) * WSEG8 + (size_t)lane * 8;
    const _Float16* bp = Xp + ((size_t)(kb0 >> 3) + gr) * 256 + m * 8;

    for (int s = 0; s < MM_KSTEPS; ++s) {
        f16x8 b0 = *(const f16x8*)(bp);
        f16x8 b1 = *(const f16x8*)(bp + 128);
        bp += 1024;
#pragma unroll
        for (int t = 0; t < 4; ++t) {
            const float* a32 = ap + (size_t)t * 16 * NROW;
            f32x4 u = __builtin_nontemporal_load((const f32x4*)a32);
            f32x4 v = __builtin_nontemporal_load((const f32x4*)(a32 + 4));
            f16x8 a;
            a[0] = (_Float16)u[0]; a[1] = (_Float16)u[1];
            a[2] = (_Float16)u[2]; a[3] = (_Float16)u[3];
            a[4] = (_Float16)v[0]; a[5] = (_Float16)v[1];
            a[6] = (_Float16)v[2]; a[7] = (_Float16)v[3];
            unsigned int p0 = __builtin_amdgcn_cvt_pk_fp8_f32(u[0] * LSCALE, u[1] * LSCALE, 0, false);
            p0 = __builtin_amdgcn_cvt_pk_fp8_f32(u[2] * LSCALE, u[3] * LSCALE, p0, true);
            unsigned int p1 = __builtin_amdgcn_cvt_pk_fp8_f32(v[0] * LSCALE, v[1] * LSCALE, 0, false);
            p1 = __builtin_amdgcn_cvt_pk_fp8_f32(v[2] * LSCALE, v[3] * LSCALE, p1, true);
            u32x2 pk; pk[0] = p0; pk[1] = p1;
            __builtin_nontemporal_store(pk, (u32x2*)(sp + t * FRAG8));
            acc[t][0] = __builtin_amdgcn_mfma_f32_16x16x32_f16(a, b0, acc[t][0], 0, 0, 0);
            acc[t][1] = __builtin_amdgcn_mfma_f32_16x16x32_f16(a, b1, acc[t][1], 0, 0, 0);
        }
        ap += 32; sp += STEP8;
    }

#pragma unroll
    for (int t = 0; t < 4; ++t)
#pragma unroll
        for (int jt = 0; jt < 2; ++jt) {
            const int row = i0 + t * 16 + gr * 4;
            _Float16* yb = Yp16 + ((size_t)kseg * NROW + row) * DIN + jt * 16 + m;
#pragma unroll
            for (int r = 0; r < 4; ++r) yb[(size_t)r * DIN] = (_Float16)acc[t][jt][r];
        }
}

// ---------------------------------------------------------------------------
// Passes 2..3: Yp16[seg] = (Lh fp8 @ (T_hi + T_lo) fp8) / 128. Round-8 proven
// shape: wave owns 64 rows, sequential 64 KB stream per (g64,kseg).
// ---------------------------------------------------------------------------
__global__ __launch_bounds__(256)
void mm_passH(const unsigned char* __restrict__ Lh,
              const unsigned char* __restrict__ Bhi,
              const unsigned char* __restrict__ Blo,
              _Float16* __restrict__ Yp16)
{
    const int wave = threadIdx.x >> 6, lane = threadIdx.x & 63;
    const int gr = lane >> 4, m = lane & 15;
    const int i0 = blockIdx.x * 256 + wave * 64;
    const int kseg = blockIdx.y;
    const int kb0 = kseg * MM_SEGK;
    const int g64 = blockIdx.x * 4 + wave;

    f32x4 acc[4][2];
#pragma unroll
    for (int t = 0; t < 4; ++t) { acc[t][0] = (f32x4)0.f; acc[t][1] = (f32x4)0.f; }

    const unsigned char* ap = Lh + ((size_t)g64 * MM_KSEG + kseg) * WSEG8 + (size_t)lane * 8;
    const unsigned char* bph = Bhi + ((size_t)(kb0 >> 3) + gr) * 256 + m * 8;
    const unsigned char* bpl = Blo + ((size_t)(kb0 >> 3) + gr) * 256 + m * 8;

#pragma unroll 2
    for (int s = 0; s < MM_KSTEPS; ++s) {
        long bh0 = *(const long*)(bph);
        long bh1 = *(const long*)(bph + 128);
        long bl0 = *(const long*)(bpl);
        long bl1 = *(const long*)(bpl + 128);
        bph += 1024; bpl += 1024;
#pragma unroll
        for (int t = 0; t < 4; ++t) {
            long at = __builtin_nontemporal_load((const long*)(ap + t * FRAG8));
            acc[t][0] = __builtin_amdgcn_mfma_f32_16x16x32_fp8_fp8(at, bh0, acc[t][0], 0, 0, 0);
            acc[t][0] = __builtin_amdgcn_mfma_f32_16x16x32_fp8_fp8(at, bl0, acc[t][0], 0, 0, 0);
            acc[t][1] = __builtin_amdgcn_mfma_f32_16x16x32_fp8_fp8(at, bh1, acc[t][1], 0, 0, 0);
            acc[t][1] = __builtin_amdgcn_mfma_f32_16x16x32_fp8_fp8(at, bl1, acc[t][1], 0, 0, 0);
        }
        ap += STEP8;
    }

#pragma unroll
    for (int t = 0; t < 4; ++t)
#pragma unroll
        for (int jt = 0; jt < 2; ++jt) {
            const int row = i0 + t * 16 + gr * 4;
            _Float16* yb = Yp16 + ((size_t)kseg * NROW + row) * DIN + jt * 16 + m;
#pragma unroll
            for (int r = 0; r < 4; ++r)
                yb[(size_t)r * DIN] = (_Float16)(acc[t][jt][r] * LSCALE_INV);
        }
}

// ---------------------------------------------------------------------------
// Epilogues 1..2: sum fp16 partials -> Y; recurrence + LP/HPc; pack next T
// to fp8 hi/lo. (Final recurrence step p=3 is fused into cheb_final.)
// ---------------------------------------------------------------------------
__global__ __launch_bounds__(256)
void cheb_epilogue(const _Float16* __restrict__ Yp16, const float* __restrict__ X,
                   const float* __restrict__ Tprev, float* __restrict__ Tnext,
                   unsigned char* __restrict__ Thi, unsigned char* __restrict__ Tlo,
                   float* __restrict__ LP, float* __restrict__ HPc,
                   float cl, float ch, float cl0, float ch0, int first)
{
    const int g = blockIdx.x * 256 + threadIdx.x;   // float4 index

    float4 y = make_float4(0.f, 0.f, 0.f, 0.f);
#pragma unroll
    for (int s = 0; s < MM_KSEG; ++s) {
        f16x4 p = *(const f16x4*)(Yp16 + (size_t)s * NROW * DIN + (size_t)g * 4);
        y.x += (float)p[0]; y.y += (float)p[1];
        y.z += (float)p[2]; y.w += (float)p[3];
    }

    float4 t;
    if (first) {
        float4 x = ((const float4*)X)[g];
        t = y;
        ((float4*)LP)[g]  = make_float4(cl0 * x.x + cl * y.x, cl0 * x.y + cl * y.y,
                                        cl0 * x.z + cl * y.z, cl0 * x.w + cl * y.w);
        ((float4*)HPc)[g] = make_float4(ch0 * x.x + ch * y.x, ch0 * x.y + ch * y.y,
                                        ch0 * x.z + ch * y.z, ch0 * x.w + ch * y.w);
    } else {
        float4 tp = ((const float4*)Tprev)[g];
        t = make_float4(2.f * y.x - tp.x, 2.f * y.y - tp.y,
                        2.f * y.z - tp.z, 2.f * y.w - tp.w);
        float4 l = ((float4*)LP)[g];
        l.x += cl * t.x; l.y += cl * t.y; l.z += cl * t.z; l.w += cl * t.w;
        ((float4*)LP)[g] = l;
        float4 h = ((float4*)HPc)[g];
        h.x += ch * t.x; h.y += ch * t.y; h.z += ch * t.z; h.w += ch * t.w;
        ((float4*)HPc)[g] = h;
    }
    ((float4*)Tnext)[g] = t;

    // pack T -> fp8 hi/lo B-layout for the next MFMA pass
    const int k = g >> 3, q = g & 7, j0 = q * 4;
    unsigned char* th = Thi + (size_t)(k >> 3) * 256 + (k & 7);
    unsigned char* tl = Tlo + (size_t)(k >> 3) * 256 + (k & 7);
    unsigned int h01 = __builtin_amdgcn_cvt_pk_fp8_f32(t.x, t.y, 0, false);
    unsigned int h23 = __builtin_amdgcn_cvt_pk_fp8_f32(t.z, t.w, 0, false);
    float rx = __builtin_amdgcn_cvt_f32_fp8(h01, 0);
    float ry = __builtin_amdgcn_cvt_f32_fp8(h01, 1);
    float rz = __builtin_amdgcn_cvt_f32_fp8(h23, 0);
    float rw = __builtin_amdgcn_cvt_f32_fp8(h23, 1);
    unsigned int l01 = __builtin_amdgcn_cvt_pk_fp8_f32(t.x - rx, t.y - ry, 0, false);
    unsigned int l23 = __builtin_amdgcn_cvt_pk_fp8_f32(t.z - rz, t.w - rw, 0, false);
    th[(j0 + 0) * 8] = (unsigned char)(h01 & 0xff);
    th[(j0 + 1) * 8] = (unsigned char)((h01 >> 8) & 0xff);
    th[(j0 + 2) * 8] = (unsigned char)(h23 & 0xff);
    th[(j0 + 3) * 8] = (unsigned char)((h23 >> 8) & 0xff);
    tl[(j0 + 0) * 8] = (unsigned char)(l01 & 0xff);
    tl[(j0 + 1) * 8] = (unsigned char)((l01 >> 8) & 0xff);
    tl[(j0 + 2) * 8] = (unsigned char)(l23 & 0xff);
    tl[(j0 + 3) * 8] = (unsigned char)((l23 >> 8) & 0xff);
}

// ---------------------------------------------------------------------------
// Fused final: reduce Yp16 (pass-3 partials) -> Y3; T3 = 2*Y3 - T1;
// LP += a3*T3; HPc += ah3*T3 (in-register, no write-back); HP = X - HPc;
// dense layers -> Z. One thread per row; 64-thread blocks (256 blocks).
// ---------------------------------------------------------------------------
__global__ __launch_bounds__(64)
void cheb_final(const _Float16* __restrict__ Yp16, const float* __restrict__ T1,
                const float* __restrict__ X, const float* __restrict__ LP,
                const float* __restrict__ HPc,
                const float* __restrict__ Wlp, const float* __restrict__ blp,
                const float* __restrict__ Whp, const float* __restrict__ bhp,
                const float* __restrict__ Wf, const float* __restrict__ bf,
                float cl, float ch, float* __restrict__ Z)
{
    const int row = blockIdx.x * 64 + threadIdx.x;
    const size_t base = (size_t)row * DIN;

    float y[DIN];
#pragma unroll
    for (int j = 0; j < DIN; ++j) y[j] = 0.f;
#pragma unroll 4
    for (int s = 0; s < MM_KSEG; ++s) {
#pragma unroll
        for (int q = 0; q < 4; ++q) {
            f16x8 p = *(const f16x8*)(Yp16 + (size_t)s * NROW * DIN + base + q * 8);
#pragma unroll
            for (int e = 0; e < 8; ++e) y[q * 8 + e] += (float)p[e];
        }
    }

    float x[DIN], lp[DIN], hp[DIN];
#pragma unroll
    for (int q = 0; q < DIN / 4; ++q) {
        float4 xv = ((const float4*)(X + base))[q];
        float4 t1 = ((const float4*)(T1 + base))[q];
        float4 lv = ((const float4*)(LP + base))[q];
        float4 hv = ((const float4*)(HPc + base))[q];
        float t3x = 2.f * y[4 * q + 0] - t1.x;
        float t3y = 2.f * y[4 * q + 1] - t1.y;
        float t3z = 2.f * y[4 * q + 2] - t1.z;
        float t3w = 2.f * y[4 * q + 3] - t1.w;
        x[4 * q + 0] = xv.x; x[4 * q + 1] = xv.y; x[4 * q + 2] = xv.z; x[4 * q + 3] = xv.w;
        lp[4 * q + 0] = lv.x + cl * t3x; lp[4 * q + 1] = lv.y + cl * t3y;
        lp[4 * q + 2] = lv.z + cl * t3z; lp[4 * q + 3] = lv.w + cl * t3w;
        hp[4 * q + 0] = xv.x - (hv.x + ch * t3x);
        hp[4 * q + 1] = xv.y - (hv.y + ch * t3y);
        hp[4 * q + 2] = xv.z - (hv.z + ch * t3z);
        hp[4 * q + 3] = xv.w - (hv.w + ch * t3w);
    }

    float h1[DIN];
#pragma unroll
    for (int j = 0; j < DIN; ++j) h1[j] = blp[j];
    for (int d = 0; d < DIN; ++d) {
        float v = lp[d];
#pragma unroll
        for (int j = 0; j < DIN; ++j) h1[j] += v * Wlp[d * DIN + j];
    }
#pragma unroll
    for (int j = 0; j < DIN; ++j) h1[j] = fmaxf(h1[j], 0.f);

    float h2[DIN];
#pragma unroll
    for (int j = 0; j < DIN; ++j) h2[j] = bhp[j];
    for (int d = 0; d < DIN; ++d) {
        float v = hp[d];
#pragma unroll
        for (int j = 0; j < DIN; ++j) h2[j] += v * Whp[d * DIN + j];
    }
#pragma unroll
    for (int j = 0; j < DIN; ++j) h2[j] = fmaxf(h2[j], 0.f);

    float z[DIN];
#pragma unroll
    for (int j = 0; j < DIN; ++j) z[j] = bf[j];
    for (int o = 0; o < DIN; ++o) {
        float v = h1[o];
#pragma unroll
        for (int j = 0; j < DIN; ++j) z[j] += v * Wf[o * DIN + j];
    }
    for (int o = 0; o < DIN; ++o) {
        float v = h2[o];
#pragma unroll
        for (int j = 0; j < DIN; ++j) z[j] += v * Wf[(DIN + o) * DIN + j];
    }
    for (int d = 0; d < DIN; ++d) {
        float v = x[d];
#pragma unroll
        for (int j = 0; j < DIN; ++j) z[j] += v * Wf[(2 * DIN + d) * DIN + j];
    }

#pragma unroll
    for (int q = 0; q < DIN / 4; ++q)
        ((float4*)(Z + base))[q] =
            make_float4(z[4 * q + 0], z[4 * q + 1], z[4 * q + 2], z[4 * q + 3]);
}

// ---------------------------------------------------------------------------
static double factd(int n) { double f = 1.0; for (int i = 2; i <= n; ++i) f *= i; return f; }

static void cheb_coeffs(double tau, double* a)
{
    for (int k = 0; k <= 8; ++k) {
        double s = 0.0;
        for (int m = 0; m < 40; ++m)
            s += pow(tau * 0.5, 2 * m + k) / (factd(m) * factd(m + k));
        a[k] = (k > 0 ? 2.0 : 1.0) * ((k & 1) ? -1.0 : 1.0) * exp(-tau) * s;
    }
}

extern "C" void kernel_launch(void* const* d_in, const int* in_sizes, int n_in,
                              void* d_out, int out_size, void* d_ws, size_t ws_size,
                              hipStream_t stream)
{
    const float* X   = (const float*)d_in[0];
    const float* L   = (const float*)d_in[1];
    const float* Wlp = (const float*)d_in[2];
    const float* blp = (const float*)d_in[3];
    const float* Whp = (const float*)d_in[4];
    const float* bhp = (const float*)d_in[5];
    const float* Wf  = (const float*)d_in[6];
    const float* bf  = (const float*)d_in[7];
    float* Z = (float*)d_out;

    const size_t TBUF = (size_t)NROW * DIN;          // 524288 elements
    char* base = (char*)d_ws;
    unsigned char* Lh = (unsigned char*)base;        // 256 MiB fp8 fragment-packed
    _Float16* Yp16 = (_Float16*)(base + (size_t)NROW * NROW);   // 16 MiB fp16 partials
    float* A   = (float*)(Yp16 + (size_t)MM_KSEG * TBUF);       // T1 (2 MiB)
    float* Bu  = A + TBUF;                                      // T2 (dead store ok)
    float* LP  = Bu + TBUF;
    float* HPc = LP + TBUF;
    unsigned char* Thi = (unsigned char*)(HPc + TBUF);          // 0.5 MiB
    unsigned char* Tlo = Thi + TBUF;                            // 0.5 MiB
    _Float16* Xp = (_Float16*)(Tlo + TBUF);                     // 1 MiB

    double alp[9], ahp[9];
    cheb_coeffs(0.5, alp);   // TAU_LP
    cheb_coeffs(1.5, ahp);   // TAU_HP

    dim3 mmGrid(NROW / 256, MM_KSEG);                // (64, 16)
    const int epiBlocks = NROW * DIN / 4 / 256;      // 512

    pack_x<<<epiBlocks, 256, 0, stream>>>(X, Xp);

    // pass 1: T1 = L @ X (f16 MFMA; emits fp8 Lh); epilogue: T1 -> A, pack
    mm_pass1<<<mmGrid, 256, 0, stream>>>(L, Xp, Yp16, Lh);
    cheb_epilogue<<<epiBlocks, 256, 0, stream>>>(Yp16, X, X, A, Thi, Tlo, LP, HPc,
        (float)alp[1], (float)ahp[1], (float)alp[0], (float)ahp[0], 1);

    // pass 2: T2 = 2 L T1 - X; epilogue packs T2 for pass 3
    mm_passH<<<mmGrid, 256, 0, stream>>>(Lh, Thi, Tlo, Yp16);
    cheb_epilogue<<<epiBlocks, 256, 0, stream>>>(Yp16, X, X, Bu, Thi, Tlo, LP, HPc,
        (float)alp[2], (float)ahp[2], 0.f, 0.f, 0);

    // pass 3: Y3 = L T2; final fuses T3 = 2Y3 - T1, LP/HPc, dense layers -> Z
    mm_passH<<<mmGrid, 256, 0, stream>>>(Lh, Thi, Tlo, Yp16);
    cheb_final<<<NROW / 64, 64, 0, stream>>>(Yp16, A, X, LP, HPc,
        Wlp, blp, Whp, bhp, Wf, bf, (float)alp[3], (float)ahp[3], Z);
}

// Round 14
// 501.856 us; speedup vs baseline: 5.1722x; 1.0079x over previous
//
#include <hip/hip_runtime.h>
#include <hip/hip_bf16.h>
#include <hip/hip_fp16.h>
#include <math.h>

#define NROW 16384
#define DIN 32

typedef _Float16 f16x8 __attribute__((ext_vector_type(8)));
typedef float f32x4 __attribute__((ext_vector_type(4)));
typedef unsigned int u32x4 __attribute__((ext_vector_type(4)));
typedef long lx2 __attribute__((ext_vector_type(2)));

constexpr int MM_KSEG = 16;
constexpr int MM_SEGK = NROW / MM_KSEG;   // 1024 k per segment
constexpr int MM_KSTEPS = MM_SEGK / 32;   // 32 mfma K-steps per segment

constexpr float LSCALE     = 128.f;       // lift L out of e4m3 subnormal range
constexpr float LSCALE_INV = 1.f / 128.f;

// ---------------------------------------------------------------------------
// fp8 Lh, PAIR-INTERLEAVED fragment packing (16 B/lane loads in passH):
//   per k-step region (2 KB): [pair p = t>>1][lane][16 B], where lane's 16 B =
//   {fragment t=2p (8 B), fragment t=2p+1 (8 B)}.
//   order: [g64=i/64][kseg][s][pair][lane][16B]; wave streams 64 KB seq.
// fp8 B (T) hi/lo interleaved: Bhl[k>>3][j][ hi: (k&7), lo: 8+(k&7) ] —
//   lane reads 16 B = {hi-long, lo-long} at ((kb>>3)+gr)*512 + (jt*16+m)*16.
// f16 B-layout (Xp, pass1): Bp[k>>3][j][k&7] halfs (unchanged).
// D (verified m89): row=(l>>4)*4+reg, col=l&15.
// ---------------------------------------------------------------------------
constexpr size_t STEP8 = 2048;                       // bytes per k-step (4 frags)
constexpr size_t WSEG8 = (size_t)MM_KSTEPS * STEP8;  // 64 KB per (g64,kseg)

// pack X (fp32 [k][32]) -> Xp fp16 packed B-layout. One float4 per thread.
__global__ __launch_bounds__(256)
void pack_x(const float* __restrict__ X, _Float16* __restrict__ Xp)
{
    const int g = blockIdx.x * 256 + threadIdx.x;
    const int k = g >> 3, q = g & 7, j0 = q * 4;
    float4 v = ((const float4*)X)[g];
    _Float16* tp = Xp + (size_t)(k >> 3) * 256 + (k & 7);
    tp[(j0 + 0) * 8] = (_Float16)v.x;
    tp[(j0 + 1) * 8] = (_Float16)v.y;
    tp[(j0 + 2) * 8] = (_Float16)v.z;
    tp[(j0 + 3) * 8] = (_Float16)v.w;
}

// ---------------------------------------------------------------------------
// Pass 1: Yp[seg] = L(fp32) @ Xp via f16 MFMA (accurate T1); emit
// Lh = e4m3(128*L) pair-interleaved. fp32 partials (clean 64 B store runs).
// ---------------------------------------------------------------------------
__global__ __launch_bounds__(256)
void mm_pass1(const float* __restrict__ L, const _Float16* __restrict__ Xp,
              float* __restrict__ Yp, unsigned char* __restrict__ Lh)
{
    const int wave = threadIdx.x >> 6, lane = threadIdx.x & 63;
    const int gr = lane >> 4, m = lane & 15;
    const int i0 = blockIdx.x * 256 + wave * 64;
    const int kseg = blockIdx.y;
    const int kb0 = kseg * MM_SEGK;
    const int g64 = blockIdx.x * 4 + wave;

    f32x4 acc[4][2];
#pragma unroll
    for (int t = 0; t < 4; ++t) { acc[t][0] = (f32x4)0.f; acc[t][1] = (f32x4)0.f; }

    const float* ap = L + (size_t)(i0 + m) * NROW + kb0 + gr * 8;
    unsigned char* sp = Lh + ((size_t)g64 * MM_KSEG + kseg) * WSEG8;
    const _Float16* bp = Xp + ((size_t)(kb0 >> 3) + gr) * 256 + m * 8;

    for (int s = 0; s < MM_KSTEPS; ++s) {
        f16x8 b0 = *(const f16x8*)(bp);
        f16x8 b1 = *(const f16x8*)(bp + 128);
        bp += 1024;
        unsigned int pe0 = 0, pe1 = 0;
#pragma unroll
        for (int t = 0; t < 4; ++t) {
            const float* a32 = ap + (size_t)t * 16 * NROW;
            f32x4 u = __builtin_nontemporal_load((const f32x4*)a32);
            f32x4 v = __builtin_nontemporal_load((const f32x4*)(a32 + 4));
            f16x8 a;
            a[0] = (_Float16)u[0]; a[1] = (_Float16)u[1];
            a[2] = (_Float16)u[2]; a[3] = (_Float16)u[3];
            a[4] = (_Float16)v[0]; a[5] = (_Float16)v[1];
            a[6] = (_Float16)v[2]; a[7] = (_Float16)v[3];
            unsigned int p0 = __builtin_amdgcn_cvt_pk_fp8_f32(u[0] * LSCALE, u[1] * LSCALE, 0, false);
            p0 = __builtin_amdgcn_cvt_pk_fp8_f32(u[2] * LSCALE, u[3] * LSCALE, p0, true);
            unsigned int p1 = __builtin_amdgcn_cvt_pk_fp8_f32(v[0] * LSCALE, v[1] * LSCALE, 0, false);
            p1 = __builtin_amdgcn_cvt_pk_fp8_f32(v[2] * LSCALE, v[3] * LSCALE, p1, true);
            if ((t & 1) == 0) { pe0 = p0; pe1 = p1; }
            else {
                u32x4 w; w[0] = pe0; w[1] = pe1; w[2] = p0; w[3] = p1;
                __builtin_nontemporal_store(w,
                    (u32x4*)(sp + (size_t)(t >> 1) * 1024 + (size_t)lane * 16));
            }
            acc[t][0] = __builtin_amdgcn_mfma_f32_16x16x32_f16(a, b0, acc[t][0], 0, 0, 0);
            acc[t][1] = __builtin_amdgcn_mfma_f32_16x16x32_f16(a, b1, acc[t][1], 0, 0, 0);
        }
        ap += 32; sp += STEP8;
    }

#pragma unroll
    for (int t = 0; t < 4; ++t)
#pragma unroll
        for (int jt = 0; jt < 2; ++jt) {
            const int row = i0 + t * 16 + gr * 4;
            float* yb = Yp + ((size_t)kseg * NROW + row) * DIN + jt * 16 + m;
#pragma unroll
            for (int r = 0; r < 4; ++r) yb[(size_t)r * DIN] = acc[t][jt][r];
        }
}

// ---------------------------------------------------------------------------
// Passes 2..3: Yp[seg] = (Lh fp8 @ (T_hi + T_lo) fp8) / 128. 16 B/lane loads:
// 2 A-loads (pair-interleaved) + 2 B-loads (hi/lo-interleaved) per k-step.
// ---------------------------------------------------------------------------
__global__ __launch_bounds__(256)
void mm_passH(const unsigned char* __restrict__ Lh,
              const unsigned char* __restrict__ Bhl,
              float* __restrict__ Yp)
{
    const int wave = threadIdx.x >> 6, lane = threadIdx.x & 63;
    const int gr = lane >> 4, m = lane & 15;
    const int i0 = blockIdx.x * 256 + wave * 64;
    const int kseg = blockIdx.y;
    const int kb0 = kseg * MM_SEGK;
    const int g64 = blockIdx.x * 4 + wave;

    f32x4 acc[4][2];
#pragma unroll
    for (int t = 0; t < 4; ++t) { acc[t][0] = (f32x4)0.f; acc[t][1] = (f32x4)0.f; }

    const unsigned char* ap = Lh + ((size_t)g64 * MM_KSEG + kseg) * WSEG8 + (size_t)lane * 16;
    const unsigned char* bp = Bhl + ((size_t)(kb0 >> 3) + gr) * 512 + (size_t)m * 16;

#pragma unroll 2
    for (int s = 0; s < MM_KSTEPS; ++s) {
        lx2 b0 = *(const lx2*)(bp);          // jt=0: {hi, lo}
        lx2 b1 = *(const lx2*)(bp + 256);    // jt=1: {hi, lo}
        bp += 2048;
        lx2 a01 = __builtin_nontemporal_load((const lx2*)(ap));          // t0, t1
        lx2 a23 = __builtin_nontemporal_load((const lx2*)(ap + 1024));   // t2, t3
        ap += STEP8;
        acc[0][0] = __builtin_amdgcn_mfma_f32_16x16x32_fp8_fp8(a01[0], b0[0], acc[0][0], 0, 0, 0);
        acc[0][0] = __builtin_amdgcn_mfma_f32_16x16x32_fp8_fp8(a01[0], b0[1], acc[0][0], 0, 0, 0);
        acc[0][1] = __builtin_amdgcn_mfma_f32_16x16x32_fp8_fp8(a01[0], b1[0], acc[0][1], 0, 0, 0);
        acc[0][1] = __builtin_amdgcn_mfma_f32_16x16x32_fp8_fp8(a01[0], b1[1], acc[0][1], 0, 0, 0);
        acc[1][0] = __builtin_amdgcn_mfma_f32_16x16x32_fp8_fp8(a01[1], b0[0], acc[1][0], 0, 0, 0);
        acc[1][0] = __builtin_amdgcn_mfma_f32_16x16x32_fp8_fp8(a01[1], b0[1], acc[1][0], 0, 0, 0);
        acc[1][1] = __builtin_amdgcn_mfma_f32_16x16x32_fp8_fp8(a01[1], b1[0], acc[1][1], 0, 0, 0);
        acc[1][1] = __builtin_amdgcn_mfma_f32_16x16x32_fp8_fp8(a01[1], b1[1], acc[1][1], 0, 0, 0);
        acc[2][0] = __builtin_amdgcn_mfma_f32_16x16x32_fp8_fp8(a23[0], b0[0], acc[2][0], 0, 0, 0);
        acc[2][0] = __builtin_amdgcn_mfma_f32_16x16x32_fp8_fp8(a23[0], b0[1], acc[2][0], 0, 0, 0);
        acc[2][1] = __builtin_amdgcn_mfma_f32_16x16x32_fp8_fp8(a23[0], b1[0], acc[2][1], 0, 0, 0);
        acc[2][1] = __builtin_amdgcn_mfma_f32_16x16x32_fp8_fp8(a23[0], b1[1], acc[2][1], 0, 0, 0);
        acc[3][0] = __builtin_amdgcn_mfma_f32_16x16x32_fp8_fp8(a23[1], b0[0], acc[3][0], 0, 0, 0);
        acc[3][0] = __builtin_amdgcn_mfma_f32_16x16x32_fp8_fp8(a23[1], b0[1], acc[3][0], 0, 0, 0);
        acc[3][1] = __builtin_amdgcn_mfma_f32_16x16x32_fp8_fp8(a23[1], b1[0], acc[3][1], 0, 0, 0);
        acc[3][1] = __builtin_amdgcn_mfma_f32_16x16x32_fp8_fp8(a23[1], b1[1], acc[3][1], 0, 0, 0);
    }

#pragma unroll
    for (int t = 0; t < 4; ++t)
#pragma unroll
        for (int jt = 0; jt < 2; ++jt) {
            const int row = i0 + t * 16 + gr * 4;
            float* yb = Yp + ((size_t)kseg * NROW + row) * DIN + jt * 16 + m;
#pragma unroll
            for (int r = 0; r < 4; ++r) yb[(size_t)r * DIN] = acc[t][jt][r] * LSCALE_INV;
        }
}

// ---------------------------------------------------------------------------
// Epilogues 1..2: sum fp32 partials -> Y; recurrence + LP/HPc; pack next T
// to interleaved fp8 hi/lo. (Recurrence step p=3 is fused into cheb_final.)
// ---------------------------------------------------------------------------
__global__ __launch_bounds__(256)
void cheb_epilogue(const float* __restrict__ Yp, const float* __restrict__ X,
                   const float* __restrict__ Tprev, float* __restrict__ Tnext,
                   unsigned char* __restrict__ Thl,
                   float* __restrict__ LP, float* __restrict__ HPc,
                   float cl, float ch, float cl0, float ch0, int first)
{
    const int g = blockIdx.x * 256 + threadIdx.x;   // float4 index
    const size_t stride = (size_t)NROW * DIN / 4;   // 131072

    float4 y = make_float4(0.f, 0.f, 0.f, 0.f);
#pragma unroll
    for (int s = 0; s < MM_KSEG; ++s) {
        float4 p = ((const float4*)Yp)[s * stride + g];
        y.x += p.x; y.y += p.y; y.z += p.z; y.w += p.w;
    }

    float4 t;
    if (first) {
        float4 x = ((const float4*)X)[g];
        t = y;
        ((float4*)LP)[g]  = make_float4(cl0 * x.x + cl * y.x, cl0 * x.y + cl * y.y,
                                        cl0 * x.z + cl * y.z, cl0 * x.w + cl * y.w);
        ((float4*)HPc)[g] = make_float4(ch0 * x.x + ch * y.x, ch0 * x.y + ch * y.y,
                                        ch0 * x.z + ch * y.z, ch0 * x.w + ch * y.w);
    } else {
        float4 tp = ((const float4*)Tprev)[g];
        t = make_float4(2.f * y.x - tp.x, 2.f * y.y - tp.y,
                        2.f * y.z - tp.z, 2.f * y.w - tp.w);
        float4 l = ((float4*)LP)[g];
        l.x += cl * t.x; l.y += cl * t.y; l.z += cl * t.z; l.w += cl * t.w;
        ((float4*)LP)[g] = l;
        float4 h = ((float4*)HPc)[g];
        h.x += ch * t.x; h.y += ch * t.y; h.z += ch * t.z; h.w += ch * t.w;
        ((float4*)HPc)[g] = h;
    }
    ((float4*)Tnext)[g] = t;

    // pack T -> interleaved fp8 hi/lo B-layout: Thl[k>>3][j][hi:(k&7) | lo:8+(k&7)]
    const int k = g >> 3, q = g & 7, j0 = q * 4;
    unsigned char* tb = Thl + (size_t)(k >> 3) * 512 + (k & 7);
    unsigned int h01 = __builtin_amdgcn_cvt_pk_fp8_f32(t.x, t.y, 0, false);
    unsigned int h23 = __builtin_amdgcn_cvt_pk_fp8_f32(t.z, t.w, 0, false);
    float rx = __builtin_amdgcn_cvt_f32_fp8(h01, 0);
    float ry = __builtin_amdgcn_cvt_f32_fp8(h01, 1);
    float rz = __builtin_amdgcn_cvt_f32_fp8(h23, 0);
    float rw = __builtin_amdgcn_cvt_f32_fp8(h23, 1);
    unsigned int l01 = __builtin_amdgcn_cvt_pk_fp8_f32(t.x - rx, t.y - ry, 0, false);
    unsigned int l23 = __builtin_amdgcn_cvt_pk_fp8_f32(t.z - rz, t.w - rw, 0, false);
    tb[(j0 + 0) * 16]     = (unsigned char)(h01 & 0xff);
    tb[(j0 + 1) * 16]     = (unsigned char)((h01 >> 8) & 0xff);
    tb[(j0 + 2) * 16]     = (unsigned char)(h23 & 0xff);
    tb[(j0 + 3) * 16]     = (unsigned char)((h23 >> 8) & 0xff);
    tb[(j0 + 0) * 16 + 8] = (unsigned char)(l01 & 0xff);
    tb[(j0 + 1) * 16 + 8] = (unsigned char)((l01 >> 8) & 0xff);
    tb[(j0 + 2) * 16 + 8] = (unsigned char)(l23 & 0xff);
    tb[(j0 + 3) * 16 + 8] = (unsigned char)((l23 >> 8) & 0xff);
}

// ---------------------------------------------------------------------------
// Fused final: reduce Yp (pass-3 fp32 partials) -> Y3; T3 = 2*Y3 - T1;
// LP += a3*T3; HPc += ah3*T3 in-register; HP = X - HPc; dense layers -> Z.
// ---------------------------------------------------------------------------
__global__ __launch_bounds__(64)
void cheb_final(const float* __restrict__ Yp, const float* __restrict__ T1,
                const float* __restrict__ X, const float* __restrict__ LP,
                const float* __restrict__ HPc,
                const float* __restrict__ Wlp, const float* __restrict__ blp,
                const float* __restrict__ Whp, const float* __restrict__ bhp,
                const float* __restrict__ Wf, const float* __restrict__ bf,
                float cl, float ch, float* __restrict__ Z)
{
    const int row = blockIdx.x * 64 + threadIdx.x;
    const size_t base = (size_t)row * DIN;

    float y[DIN];
#pragma unroll
    for (int j = 0; j < DIN; ++j) y[j] = 0.f;
#pragma unroll 4
    for (int s = 0; s < MM_KSEG; ++s) {
        const float4* yp = (const float4*)(Yp + (size_t)s * NROW * DIN + base);
#pragma unroll
        for (int q = 0; q < 8; ++q) {
            float4 p = yp[q];
            y[4 * q + 0] += p.x; y[4 * q + 1] += p.y;
            y[4 * q + 2] += p.z; y[4 * q + 3] += p.w;
        }
    }

    float x[DIN], lp[DIN], hp[DIN];
#pragma unroll
    for (int q = 0; q < DIN / 4; ++q) {
        float4 xv = ((const float4*)(X + base))[q];
        float4 t1 = ((const float4*)(T1 + base))[q];
        float4 lv = ((const float4*)(LP + base))[q];
        float4 hv = ((const float4*)(HPc + base))[q];
        float t3x = 2.f * y[4 * q + 0] - t1.x;
        float t3y = 2.f * y[4 * q + 1] - t1.y;
        float t3z = 2.f * y[4 * q + 2] - t1.z;
        float t3w = 2.f * y[4 * q + 3] - t1.w;
        x[4 * q + 0] = xv.x; x[4 * q + 1] = xv.y; x[4 * q + 2] = xv.z; x[4 * q + 3] = xv.w;
        lp[4 * q + 0] = lv.x + cl * t3x; lp[4 * q + 1] = lv.y + cl * t3y;
        lp[4 * q + 2] = lv.z + cl * t3z; lp[4 * q + 3] = lv.w + cl * t3w;
        hp[4 * q + 0] = xv.x - (hv.x + ch * t3x);
        hp[4 * q + 1] = xv.y - (hv.y + ch * t3y);
        hp[4 * q + 2] = xv.z - (hv.z + ch * t3z);
        hp[4 * q + 3] = xv.w - (hv.w + ch * t3w);
    }

    float h1[DIN];
#pragma unroll
    for (int j = 0; j < DIN; ++j) h1[j] = blp[j];
    for (int d = 0; d < DIN; ++d) {
        float v = lp[d];
#pragma unroll
        for (int j = 0; j < DIN; ++j) h1[j] += v * Wlp[d * DIN + j];
    }
#pragma unroll
    for (int j = 0; j < DIN; ++j) h1[j] = fmaxf(h1[j], 0.f);

    float h2[DIN];
#pragma unroll
    for (int j = 0; j < DIN; ++j) h2[j] = bhp[j];
    for (int d = 0; d < DIN; ++d) {
        float v = hp[d];
#pragma unroll
        for (int j = 0; j < DIN; ++j) h2[j] += v * Whp[d * DIN + j];
    }
#pragma unroll
    for (int j = 0; j < DIN; ++j) h2[j] = fmaxf(h2[j], 0.f);

    float z[DIN];
#pragma unroll
    for (int j = 0; j < DIN; ++j) z[j] = bf[j];
    for (int o = 0; o < DIN; ++o) {
        float v = h1[o];
#pragma unroll
        for (int j = 0; j < DIN; ++j) z[j] += v * Wf[o * DIN + j];
    }
    for (int o = 0; o < DIN; ++o) {
        float v = h2[o];
#pragma unroll
        for (int j = 0; j < DIN; ++j) z[j] += v * Wf[(DIN + o) * DIN + j];
    }
    for (int d = 0; d < DIN; ++d) {
        float v = x[d];
#pragma unroll
        for (int j = 0; j < DIN; ++j) z[j] += v * Wf[(2 * DIN + d) * DIN + j];
    }

#pragma unroll
    for (int q = 0; q < DIN / 4; ++q)
        ((float4*)(Z + base))[q] =
            make_float4(z[4 * q + 0], z[4 * q + 1], z[4 * q + 2], z[4 * q + 3]);
}

// ---------------------------------------------------------------------------
static double factd(int n) { double f = 1.0; for (int i = 2; i <= n; ++i) f *= i; return f; }

static void cheb_coeffs(double tau, double* a)
{
    for (int k = 0; k <= 8; ++k) {
        double s = 0.0;
        for (int m = 0; m < 40; ++m)
            s += pow(tau * 0.5, 2 * m + k) / (factd(m) * factd(m + k));
        a[k] = (k > 0 ? 2.0 : 1.0) * ((k & 1) ? -1.0 : 1.0) * exp(-tau) * s;
    }
}

extern "C" void kernel_launch(void* const* d_in, const int* in_sizes, int n_in,
                              void* d_out, int out_size, void* d_ws, size_t ws_size,
                              hipStream_t stream)
{
    const float* X   = (const float*)d_in[0];
    const float* L   = (const float*)d_in[1];
    const float* Wlp = (const float*)d_in[2];
    const float* blp = (const float*)d_in[3];
    const float* Whp = (const float*)d_in[4];
    const float* bhp = (const float*)d_in[5];
    const float* Wf  = (const float*)d_in[6];
    const float* bf  = (const float*)d_in[7];
    float* Z = (float*)d_out;

    const size_t TBUF = (size_t)NROW * DIN;          // 524288 elements
    char* base = (char*)d_ws;
    unsigned char* Lh = (unsigned char*)base;        // 256 MiB fp8 pair-interleaved
    float* Yp  = (float*)(base + (size_t)NROW * NROW);      // 16 x 2 MiB fp32 partials
    float* A   = Yp + (size_t)MM_KSEG * TBUF;               // T1 (2 MiB)
    float* Bu  = A + TBUF;                                  // T2 (unused downstream)
    float* LP  = Bu + TBUF;
    float* HPc = LP + TBUF;
    unsigned char* Thl = (unsigned char*)(HPc + TBUF);      // 1 MiB hi/lo interleaved
    _Float16* Xp = (_Float16*)(Thl + 2 * TBUF);             // 1 MiB

    double alp[9], ahp[9];
    cheb_coeffs(0.5, alp);   // TAU_LP
    cheb_coeffs(1.5, ahp);   // TAU_HP

    dim3 mmGrid(NROW / 256, MM_KSEG);                // (64, 16)
    const int epiBlocks = NROW * DIN / 4 / 256;      // 512

    pack_x<<<epiBlocks, 256, 0, stream>>>(X, Xp);

    // pass 1: T1 = L @ X (f16 MFMA; emits fp8 Lh); epilogue: T1 -> A, pack
    mm_pass1<<<mmGrid, 256, 0, stream>>>(L, Xp, Yp, Lh);
    cheb_epilogue<<<epiBlocks, 256, 0, stream>>>(Yp, X, X, A, Thl, LP, HPc,
        (float)alp[1], (float)ahp[1], (float)alp[0], (float)ahp[0], 1);

    // pass 2: T2 = 2 L T1 - X; epilogue packs T2 for pass 3
    mm_passH<<<mmGrid, 256, 0, stream>>>(Lh, Thl, Yp);
    cheb_epilogue<<<epiBlocks, 256, 0, stream>>>(Yp, X, X, Bu, Thl, LP, HPc,
        (float)alp[2], (float)ahp[2], 0.f, 0.f, 0);

    // pass 3: Y3 = L T2; final fuses T3 = 2Y3 - T1, LP/HPc, dense layers -> Z
    mm_passH<<<mmGrid, 256, 0, stream>>>(Lh, Thl, Yp);
    cheb_final<<<NROW / 64, 64, 0, stream>>>(Yp, A, X, LP, HPc,
        Wlp, blp, Whp, bhp, Wf, bf, (float)alp[3], (float)ahp[3], Z);
}